// Round 5
// baseline (3307.068 us; speedup 1.0000x reference)
//
#include <hip/hip_runtime.h>
#include <hip/hip_bf16.h>

// NS solver: 256x256 periodic, B=8, NC=3 (u,v,density), T outer x 10 inner steps.
// Established: y0 = fp32 (R1 NaN proof), dt = fp32 (R2==R3 bit-identical proof),
// out = fp32 (R4 analysis: reference output dtype is float32; bit-identical err
// across different FFT impls was my own bf16 write quantization echoing back).
//
// FFT: textbook radix-2, in-place in LDS, twiddles via __sincosf (no tables).
// Forward = DIT (bit-reversed load -> natural out). Inverse = DIF (natural in
// -> bit-reversed out, un-reversed at the store). Hand-verified at N=4.
//
// ws aliasing (12.6 MB total = 2 banks x 3 fields):
//   step reads bank X, writes bank Y. After advect, bank X fields are dead:
//     S (FIELD*BATCH float2 = 4 MB) := [Vx, Dx]   (V,D contiguous in a bank)
//     Q (2 MB)                      := Ux
//   All kernels are sequential on one stream; bank X is rewritten only by the
//   NEXT step's advect, after correct_uv consumed Q.

#define NN 256
#define NM 255
#define FIELD (NN*NN)
#define BATCH 8
#define TOTAL (BATCH*FIELD)
#define TEAMS 8

constexpr float RDX  = 40.743665431525205f;   // N/(2*pi) = 1/DX
constexpr float VISC = 1e-3f;

__device__ __forceinline__ int rev8(int x) { return (int)(__brev((unsigned)x) >> 24); }

__device__ __forceinline__ float decode_dt(const unsigned* dtw) {
  unsigned w = dtw[0];
  float cf = __uint_as_float(w);
  float cb = __uint_as_float((w & 0xFFFFu) << 16);
  bool v32 = (cf > 1e-8f) && (cf < 1.0f);          // NaN-safe
  bool vbf = (cb > 1e-8f) && (cb < 1.0f);
  return v32 ? cf : (vbf ? cb : 1e-3f);
}

// ---------------------------------------------------------------- advection
__device__ __forceinline__ float face_flux(float uf, float cm, float c0,
                                           float cp, float cpp, float hdtdx) {
  float dc = cp - c0;
  float f_low  = (uf >= 0.0f) ? uf*c0 : uf*cp;
  float f_high = uf*0.5f*(c0+cp) - hdtdx*uf*uf*dc;
  float dc_up  = (uf >= 0.0f) ? (c0 - cm) : (cpp - cp);
  float dc_safe = (fabsf(dc) > 1e-12f) ? dc : 1e-12f;
  float r = dc_up / dc_safe;
  float phi = (r > 0.0f) ? (2.0f*r/(1.0f+r)) : 0.0f;
  return f_low + phi*(f_high - f_low);
}

__global__ __launch_bounds__(256) void advect_kernel(
    const float* __restrict__ U, const float* __restrict__ V, const float* __restrict__ D,
    float* __restrict__ Uo, float* __restrict__ Vo, float* __restrict__ Do_,
    const unsigned* __restrict__ dtw)
{
  int idx = blockIdx.x*256 + threadIdx.x;
  int j = idx & NM;
  int i = (idx >> 8) & NM;
  int base = (idx >> 16) * FIELD;
  float dt = decode_dt(dtw);
  float hdtdx = 0.5f*dt*RDX;

  const float* Ub = U + base;
  const float* Vb = V + base;
  const float* Db = D + base;

  int im2 = ((i-2)&NM)*NN, im1 = ((i-1)&NM)*NN, i0r = i*NN,
      ip1 = ((i+1)&NM)*NN, ip2 = ((i+2)&NM)*NN;
  int jm2 = (j-2)&NM, jm1 = (j-1)&NM, jp1 = (j+1)&NM, jp2 = (j+2)&NM;

  float u_c  = Ub[i0r+j];
  float u_im2= Ub[im2+j], u_im1 = Ub[im1+j], u_ip1 = Ub[ip1+j], u_ip2 = Ub[ip2+j];
  float u_jm2= Ub[i0r+jm2], u_jm1 = Ub[i0r+jm1], u_jp1 = Ub[i0r+jp1], u_jp2 = Ub[i0r+jp2];
  float v_c  = Vb[i0r+j];
  float v_im2= Vb[im2+j], v_im1 = Vb[im1+j], v_ip1 = Vb[ip1+j], v_ip2 = Vb[ip2+j];
  float v_jm2= Vb[i0r+jm2], v_jm1 = Vb[i0r+jm1], v_jp1 = Vb[i0r+jp1], v_jp2 = Vb[i0r+jp2];
  float d_c  = Db[i0r+j];
  float d_im2= Db[im2+j], d_im1 = Db[im1+j], d_ip1 = Db[ip1+j], d_ip2 = Db[ip2+j];
  float d_jm2= Db[i0r+jm2], d_jm1 = Db[i0r+jm1], d_jp1 = Db[i0r+jp1], d_jp2 = Db[i0r+jp2];

  // face velocities (axis i uses u, axis j uses v) shared by all 3 fields
  float ufI0 = 0.5f*(u_c + u_ip1);
  float ufIm = 0.5f*(u_im1 + u_c);
  float vfJ0 = 0.5f*(v_c + v_jp1);
  float vfJm = 0.5f*(v_jm1 + v_c);

  float tu = -(( face_flux(ufI0, u_im1, u_c, u_ip1, u_ip2, hdtdx)
               - face_flux(ufIm, u_im2, u_im1, u_c, u_ip1, hdtdx))
             + ( face_flux(vfJ0, u_jm1, u_c, u_jp1, u_jp2, hdtdx)
               - face_flux(vfJm, u_jm2, u_jm1, u_c, u_jp1, hdtdx))) * RDX;
  float lapu = (u_im1 + u_ip1 + u_jm1 + u_jp1 - 4.0f*u_c) * (RDX*RDX);

  float tv = -(( face_flux(ufI0, v_im1, v_c, v_ip1, v_ip2, hdtdx)
               - face_flux(ufIm, v_im2, v_im1, v_c, v_ip1, hdtdx))
             + ( face_flux(vfJ0, v_jm1, v_c, v_jp1, v_jp2, hdtdx)
               - face_flux(vfJm, v_jm2, v_jm1, v_c, v_jp1, hdtdx))) * RDX;
  float lapv = (v_im1 + v_ip1 + v_jm1 + v_jp1 - 4.0f*v_c) * (RDX*RDX);

  float td = -(( face_flux(ufI0, d_im1, d_c, d_ip1, d_ip2, hdtdx)
               - face_flux(ufIm, d_im2, d_im1, d_c, d_ip1, hdtdx))
             + ( face_flux(vfJ0, d_jm1, d_c, d_jp1, d_jp2, hdtdx)
               - face_flux(vfJm, d_jm2, d_jm1, d_c, d_jp1, hdtdx))) * RDX;

  Uo[idx] = u_c + dt*(tu + VISC*lapu);
  Vo[idx] = v_c + dt*(tv + VISC*lapv);
  Do_[idx] = d_c + dt*td;
}

// ---------------------------------------------------------------- FFT cores
// Forward: in-place radix-2 DIT. Input must be pre-loaded in BIT-REVERSED
// order; output is natural order.
__device__ __forceinline__ void fft256_dit_fwd(float2* __restrict__ A, int lane)
{
  #pragma unroll
  for (int s = 1; s <= 8; ++s) {
    int L = 1 << s, half = L >> 1;
    float angscale = -6.28318530717958647692f / (float)L;
    #pragma unroll
    for (int r = 0; r < 4; ++r) {
      int bfly = lane + (r << 5);             // 0..127
      int q = bfly & (half - 1);
      int g = (bfly >> (s - 1)) << s;         // (bfly/half)*L
      float sw, cw;
      __sincosf(angscale * (float)q, &sw, &cw);
      float2 a = A[g + q];
      float2 b = A[g + q + half];
      float wbx = cw*b.x - sw*b.y;
      float wby = cw*b.y + sw*b.x;
      A[g + q]        = make_float2(a.x + wbx, a.y + wby);
      A[g + q + half] = make_float2(a.x - wbx, a.y - wby);
    }
    __syncthreads();
  }
}

// Inverse (unnormalized): in-place radix-2 DIF. Input natural order; output
// BIT-REVERSED.
__device__ __forceinline__ void fft256_dif_inv(float2* __restrict__ A, int lane)
{
  #pragma unroll
  for (int s = 8; s >= 1; --s) {
    int L = 1 << s, half = L >> 1;
    float angscale = 6.28318530717958647692f / (float)L;
    #pragma unroll
    for (int r = 0; r < 4; ++r) {
      int bfly = lane + (r << 5);
      int q = bfly & (half - 1);
      int g = (bfly >> (s - 1)) << s;
      float sw, cw;
      __sincosf(angscale * (float)q, &sw, &cw);
      float2 a = A[g + q];
      float2 b = A[g + q + half];
      float dx = a.x - b.x, dy = a.y - b.y;
      A[g + q]        = make_float2(a.x + b.x, a.y + b.y);
      A[g + q + half] = make_float2(cw*dx - sw*dy, cw*dy + sw*dx);
    }
    __syncthreads();
  }
}

// div(u,v) -> forward row FFT (over j) -> S[i][k2]
__global__ __launch_bounds__(256) void fft_rows_div(
    const float* __restrict__ U2, const float* __restrict__ V2,
    float2* __restrict__ S)
{
  __shared__ float2 Ab[TEAMS][NN];
  int tid = threadIdx.x;
  int b = blockIdx.x >> 5;
  int row0 = (blockIdx.x & 31) << 3;
  const float* Ub = U2 + b*FIELD;
  const float* Vb = V2 + b*FIELD;
  int jm1 = (tid - 1) & NM;
  int rj = rev8(tid);
  #pragma unroll
  for (int k = 0; k < 8; ++k) {
    int row = row0 + k;
    int rm1 = (row - 1) & NM;
    float dv = (Ub[row*NN + tid] - Ub[rm1*NN + tid]
              + Vb[row*NN + tid] - Vb[row*NN + jm1]) * RDX;
    Ab[k][rj] = make_float2(dv, 0.0f);       // bit-reversed load for DIT
  }
  __syncthreads();
  int g = tid >> 5, lane = tid & 31;
  fft256_dit_fwd(Ab[g], lane);
  float2* Sb = S + b*FIELD;
  #pragma unroll
  for (int k = 0; k < 8; ++k)
    Sb[(row0 + k)*NN + tid] = Ab[k][tid];    // natural order out
}

// forward col FFT (over i) -> * invLam/65536 -> inverse col FFT, in place
__global__ __launch_bounds__(256) void fft_cols(float2* __restrict__ S)
{
  __shared__ float2 Ab[TEAMS][NN];
  int tid = threadIdx.x;
  int b = blockIdx.x >> 5;
  int col0 = (blockIdx.x & 31) << 3;
  float2* Sb = S + b*FIELD;
  #pragma unroll
  for (int k = 0; k < 8; ++k) {
    int idx = tid + (k << 8);
    int i = idx >> 3, c = idx & 7;
    Ab[c][rev8(i)] = Sb[i*NN + col0 + c];    // bit-reversed load for DIT
  }
  __syncthreads();
  int g = tid >> 5, lane = tid & 31;
  fft256_dit_fwd(Ab[g], lane);               // -> natural k1
  int k2 = col0 + g;
  float s2 = __sinf(0.01227184630308512983f * (float)k2);   // pi/256 * k2
  float l2 = -4.0f * s2 * s2 * (RDX*RDX);    // lam1[k2] = (2cos(2pi k/N)-2)/DX^2
  #pragma unroll
  for (int r = 0; r < 8; ++r) {
    int k1 = lane + (r << 5);
    float s1 = __sinf(0.01227184630308512983f * (float)k1);
    float l1 = -4.0f * s1 * s1 * (RDX*RDX);
    float den = l1 + l2;
    float sc = ((k1 | k2) == 0) ? 0.0f : (1.0f/den);
    sc *= (1.0f/65536.0f);                   // fold in ifft2's 1/N^2
    float2 v = Ab[g][k1];
    Ab[g][k1] = make_float2(v.x*sc, v.y*sc);
  }
  __syncthreads();
  fft256_dif_inv(Ab[g], lane);               // natural in -> bit-reversed out
  #pragma unroll
  for (int k = 0; k < 8; ++k) {
    int idx = tid + (k << 8);
    int i = idx >> 3, c = idx & 7;
    Sb[i*NN + col0 + c] = Ab[c][rev8(i)];    // un-reverse on store
  }
}

// inverse row FFT -> q (real part)
__global__ __launch_bounds__(256) void fft_rows_inv(
    const float2* __restrict__ S, float* __restrict__ Q)
{
  __shared__ float2 Ab[TEAMS][NN];
  int tid = threadIdx.x;
  int b = blockIdx.x >> 5;
  int row0 = (blockIdx.x & 31) << 3;
  const float2* Sb = S + b*FIELD;
  #pragma unroll
  for (int k = 0; k < 8; ++k)
    Ab[k][tid] = Sb[(row0 + k)*NN + tid];    // natural order in (DIF)
  __syncthreads();
  int g = tid >> 5, lane = tid & 31;
  fft256_dif_inv(Ab[g], lane);
  float* Qb = Q + b*FIELD;
  int rj = rev8(tid);
  #pragma unroll
  for (int k = 0; k < 8; ++k)
    Qb[(row0 + k)*NN + tid] = Ab[k][rj].x;   // un-reverse on store
}

// ---------------------------------------------------------------- misc
__global__ __launch_bounds__(256) void correct_uv(
    float* __restrict__ U2, float* __restrict__ V2, const float* __restrict__ Q)
{
  int idx = blockIdx.x*256 + threadIdx.x;
  int j = idx & NM;
  int i = (idx >> 8) & NM;
  int base = (idx >> 16) * FIELD;
  const float* Qb = Q + base;
  float q0 = Qb[i*NN + j];
  float qi = Qb[((i+1)&NM)*NN + j];
  float qj = Qb[i*NN + ((j+1)&NM)];
  U2[idx] -= (qi - q0)*RDX;
  V2[idx] -= (qj - q0)*RDX;
}

__global__ __launch_bounds__(256) void write_out(
    const float* __restrict__ U, const float* __restrict__ V, const float* __restrict__ D,
    float* __restrict__ out, int t, int T)
{
  int idx = blockIdx.x*256 + threadIdx.x;
  int b = idx >> 16;
  int pos = idx & (FIELD-1);
  size_t o = ((size_t)(b*T + t)*FIELD + pos)*3u;
  out[o]   = U[idx];
  out[o+1] = V[idx];
  out[o+2] = D[idx];
}

__global__ __launch_bounds__(256) void init_state(
    const float* __restrict__ y0,
    float* __restrict__ U, float* __restrict__ V, float* __restrict__ D)
{
  int idx = blockIdx.x*256 + threadIdx.x;
  U[idx] = y0[idx*3];
  V[idx] = y0[idx*3+1];
  D[idx] = y0[idx*3+2];
}

// ---------------------------------------------------------------- launch
extern "C" void kernel_launch(void* const* d_in, const int* in_sizes, int n_in,
                              void* d_out, int out_size, void* d_ws, size_t ws_size,
                              hipStream_t stream) {
  (void)in_sizes; (void)n_in; (void)ws_size;
  const float*    y0  = (const float*)d_in[0];
  const unsigned* dtw = (const unsigned*)d_in[1];
  float* out = (float*)d_out;

  int T = out_size / (3*FIELD*BATCH);
  if (T < 1) T = 1;

  float* ws = (float*)d_ws;
  float* bank0 = ws;              // U,V,D contiguous (TOTAL floats each)
  float* bank1 = ws + 3*TOTAL;
  // total ws use: 6*TOTAL floats = 12.58 MB

  init_state<<<TOTAL/256, 256, 0, stream>>>(y0, bank0, bank0+TOTAL, bank0+2*TOTAL);

  float* inb = bank0;
  float* outb = bank1;
  for (int t = 0; t < T; ++t) {
    for (int s = 0; s < 10; ++s) {
      float *Ui = inb,  *Vi = inb + TOTAL,  *Di = inb + 2*TOTAL;
      float *Uo = outb, *Vo = outb + TOTAL, *Do_ = outb + 2*TOTAL;
      float2* S = (float2*)(inb + TOTAL);   // aliases dead Vi,Di (4 MB)
      float*  Q = inb;                      // aliases dead Ui (2 MB)
      advect_kernel<<<TOTAL/256, 256, 0, stream>>>(Ui, Vi, Di, Uo, Vo, Do_, dtw);
      fft_rows_div <<<BATCH*32, 256, 0, stream>>>(Uo, Vo, S);
      fft_cols     <<<BATCH*32, 256, 0, stream>>>(S);
      fft_rows_inv <<<BATCH*32, 256, 0, stream>>>(S, Q);
      correct_uv   <<<TOTAL/256, 256, 0, stream>>>(Uo, Vo, Q);
      float* tmp = inb; inb = outb; outb = tmp;
    }
    write_out<<<TOTAL/256, 256, 0, stream>>>(inb, inb+TOTAL, inb+2*TOTAL, out, t, T);
  }
}